// Round 1
// baseline (318.297 us; speedup 1.0000x reference)
//
#include <hip/hip_runtime.h>

#define BATCH     131072
#define DIM       256
#define NBLOCKS   2048
#define TPB       256
#define WPB       (TPB / 64)            // waves per block = 4
#define TOTWAVES  (NBLOCKS * WPB)       // 8192 waves; 16 rows per wave

// One wave owns one row per iteration: lane i holds cols [4i, 4i+3] as float4.
// Row-scalar quantities (x0, s = theta . x[1..6]) come from lanes 0/1 via shuffle.
__global__ __launch_bounds__(TPB) void rotor_main(
    const float* __restrict__ A,      // state_a [BATCH][DIM]
    const float* __restrict__ Bst,    // state_b [BATCH][DIM]
    const float* __restrict__ theta,  // [6]
    float* __restrict__ out,          // transformed [BATCH][DIM]
    float* __restrict__ partials)     // [NBLOCKS] squared-diff partial sums
{
    // Uniform coefficient computation (theta loads are wave-uniform -> cached).
    const float t0 = theta[0], t1 = theta[1], t2 = theta[2];
    const float t3 = theta[3], t4 = theta[4], t5 = theta[5];
    const float a2 = t0*t0 + t1*t1 + t2*t2 + t3*t3 + t4*t4 + t5*t5;
    float alpha, beta, gamma;
    if (a2 < 1e-30f) {              // lim a->0: R = I (terms vanish anyway; avoid 0/0)
        alpha = 0.5f; beta = 0.0f; gamma = -0.125f;
    } else {
        const float a = sqrtf(a2);
        const float s = sinf(0.5f * a);
        const float c = cosf(0.5f * a);
        alpha = s / a;              // sin(t)/a
        beta  = c - 1.0f;           // cos(t)-1
        gamma = beta / a2;          // (cos(t)-1)/a^2
    }

    const int lane = threadIdx.x & 63;
    const int wid  = threadIdx.x >> 6;
    const int gw   = blockIdx.x * WPB + wid;

    float acc = 0.0f;
    for (int row = gw; row < BATCH; row += TOTWAVES) {
        const size_t base = (size_t)row * DIM;
        const float4 a4 = ((const float4*)(A   + base))[lane];
        const float4 b4 = ((const float4*)(Bst + base))[lane];

        // sparse dot s = theta . x[1..6]; x[1..6] live in lanes 0 and 1
        float p = 0.0f;
        if (lane == 0)      p = t0*a4.y + t1*a4.z + t2*a4.w;
        else if (lane == 1) p = t3*a4.x + t4*a4.y + t5*a4.z;
        const float sv = __shfl(p, 0, 64) + __shfl(p, 1, 64);
        const float x0 = __shfl(a4.x, 0, 64);
        const float w  = gamma * sv - alpha * x0;   // coefficient of theta_k for k=1..6

        float4 o = a4;
        if (lane == 0) {
            o.x = x0 + beta * x0 + alpha * sv;      // cos(t)*x0 + alpha*s
            o.y = a4.y + t0 * w;
            o.z = a4.z + t1 * w;
            o.w = a4.w + t2 * w;
        } else if (lane == 1) {
            o.x = a4.x + t3 * w;
            o.y = a4.y + t4 * w;
            o.z = a4.z + t5 * w;
            // o.w = col 7, unchanged
        }
        ((float4*)(out + base))[lane] = o;

        const float dx = o.x - b4.x, dy = o.y - b4.y;
        const float dz = o.z - b4.z, dw = o.w - b4.w;
        acc += dx*dx + dy*dy + dz*dz + dw*dw;
    }

    // wave reduce -> block reduce -> one partial per block (no atomics)
    #pragma unroll
    for (int off = 32; off > 0; off >>= 1) acc += __shfl_xor(acc, off, 64);
    __shared__ float smem[WPB];
    if (lane == 0) smem[wid] = acc;
    __syncthreads();
    if (threadIdx.x == 0) {
        float s = 0.0f;
        #pragma unroll
        for (int i = 0; i < WPB; ++i) s += smem[i];
        partials[blockIdx.x] = s;
    }
}

// Final reduction WRITES the loss slot (d_out is poisoned 0xAA, so never accumulate into it).
__global__ __launch_bounds__(256) void rotor_loss(
    const float* __restrict__ partials, float* __restrict__ loss)
{
    const int tid = threadIdx.x;
    double acc = 0.0;
    for (int i = tid; i < NBLOCKS; i += 256) acc += (double)partials[i];
    #pragma unroll
    for (int off = 32; off > 0; off >>= 1) acc += __shfl_xor(acc, off, 64);
    __shared__ double smem[4];
    const int lane = tid & 63, wid = tid >> 6;
    if (lane == 0) smem[wid] = acc;
    __syncthreads();
    if (tid == 0) {
        const double s = smem[0] + smem[1] + smem[2] + smem[3];
        *loss = (float)(s / (double)((size_t)BATCH * (size_t)DIM));
    }
}

extern "C" void kernel_launch(void* const* d_in, const int* in_sizes, int n_in,
                              void* d_out, int out_size, void* d_ws, size_t ws_size,
                              hipStream_t stream) {
    const float* A     = (const float*)d_in[0];   // state_a, 131072*256
    const float* Bst   = (const float*)d_in[1];   // state_b, 131072*256
    const float* theta = (const float*)d_in[2];   // bivector_coeffs, 6

    float* out      = (float*)d_out;                      // transformed, then loss
    float* loss     = out + (size_t)BATCH * (size_t)DIM;  // d_out[33554432]
    float* partials = (float*)d_ws;                       // NBLOCKS floats

    rotor_main<<<NBLOCKS, TPB, 0, stream>>>(A, Bst, theta, out, partials);
    rotor_loss<<<1, 256, 0, stream>>>(partials, loss);
}